// Round 1
// baseline (276.665 us; speedup 1.0000x reference)
//
#include <hip/hip_runtime.h>

// Problem constants (fixed by the reference)
#define B_  2
#define S_  2048
#define D_  1024
#define H_  16
#define HD_ 64
#define M_  (B_*S_)   // 4096 rows in all GEMMs

typedef __attribute__((ext_vector_type(8))) short s16x8;   // 8 bf16 (4 VGPRs) MFMA operand
typedef __attribute__((ext_vector_type(4))) float f32x4;   // MFMA accumulator

__device__ __forceinline__ unsigned short f2bf(float f) {
  unsigned int u = __builtin_bit_cast(unsigned int, f);
  u += 0x7fffu + ((u >> 16) & 1u);          // round-to-nearest-even
  return (unsigned short)(u >> 16);
}
__device__ __forceinline__ float bf2f(unsigned short h) {
  unsigned int u = ((unsigned int)h) << 16;
  return __builtin_bit_cast(float, u);
}

// ---------------- elementwise f32 -> bf16 (x4 vectorized) ----------------
__global__ void cvt_kernel(const float* __restrict__ in, unsigned short* __restrict__ out, int n4) {
  int i = blockIdx.x * blockDim.x + threadIdx.x;
  if (i >= n4) return;
  float4 v = reinterpret_cast<const float4*>(in)[i];
  ushort4 o;
  o.x = f2bf(v.x); o.y = f2bf(v.y); o.z = f2bf(v.z); o.w = f2bf(v.w);
  reinterpret_cast<ushort4*>(out)[i] = o;
}

// ---------------- 1024x1024 transpose + convert: out[n][k] = in[k][n] ----------------
__global__ void transpose_cvt(const float* __restrict__ in, unsigned short* __restrict__ out) {
  __shared__ float tile[32][33];
  const int bx = blockIdx.x;   // input col tile (n)
  const int by = blockIdx.y;   // input row tile (k)
  const int tx = threadIdx.x;
  const int x = bx * 32 + tx;  // n
  for (int j = threadIdx.y; j < 32; j += 8) {
    tile[j][tx] = in[(by * 32 + j) * 1024 + x];   // in[k][n], coalesced
  }
  __syncthreads();
  const int xo = by * 32 + tx; // k (output col)
  for (int j = threadIdx.y; j < 32; j += 8) {
    out[(bx * 32 + j) * 1024 + xo] = f2bf(tile[tx][j]);  // out[n][k], coalesced
  }
}

// ---------------- bf16 MFMA GEMM, C[M,N] = A[M,K] * B[K,N] ----------------
// A: bf16 [4096][1024] row-major.  Bt: bf16 [N][K] ("B^T layout": row n = column n of B).
// mode 0: write bf16 scattered to [b,h,s,hd] (Q/K/V projection), acc*scale.
// mode 1: write f32 [m][n] = acc + bias[n].
#define BM 128
#define BN 128
#define BK 64

__global__ __launch_bounds__(256) void gemm_bt(
    const unsigned short* __restrict__ A,
    const unsigned short* __restrict__ Bt,
    void* __restrict__ outp,
    const float* __restrict__ bias,
    const int mode, const float scale)
{
  __shared__ unsigned short As[BM][BK + 8];   // +8 keeps 16B alignment, breaks bank stride
  __shared__ unsigned short Bs[BN][BK + 8];

  const int t    = threadIdx.x;
  const int lane = t & 63;
  const int wid  = t >> 6;
  const int l15  = lane & 15;
  const int g    = lane >> 4;
  const int wm   = wid >> 1;   // 2x2 waves, each 64x64
  const int wn   = wid & 1;

  const int n0 = blockIdx.x * BN;
  const int m0 = blockIdx.y * BM;

  f32x4 acc[4][4];
#pragma unroll
  for (int i = 0; i < 4; ++i)
#pragma unroll
    for (int j = 0; j < 4; ++j)
      acc[i][j] = (f32x4){0.f, 0.f, 0.f, 0.f};

  for (int kt = 0; kt < 1024 / BK; ++kt) {
    const int k0 = kt * BK;
    // stage A,B tiles: 128x64 bf16 each, 32 elems (4 x 16B) per thread
#pragma unroll
    for (int p = 0; p < 4; ++p) {
      const int lin = p * 256 + t;
      const int row = lin >> 3;
      const int col = (lin & 7) * 8;
      *reinterpret_cast<s16x8*>(&As[row][col]) =
          *reinterpret_cast<const s16x8*>(&A[(m0 + row) * 1024 + k0 + col]);
      *reinterpret_cast<s16x8*>(&Bs[row][col]) =
          *reinterpret_cast<const s16x8*>(&Bt[(n0 + row) * 1024 + k0 + col]);
    }
    __syncthreads();

#pragma unroll
    for (int kk = 0; kk < 2; ++kk) {
      s16x8 af[4], bf[4];
#pragma unroll
      for (int mi = 0; mi < 4; ++mi)
        af[mi] = *reinterpret_cast<const s16x8*>(&As[wm * 64 + mi * 16 + l15][kk * 32 + 8 * g]);
#pragma unroll
      for (int ni = 0; ni < 4; ++ni)
        bf[ni] = *reinterpret_cast<const s16x8*>(&Bs[wn * 64 + ni * 16 + l15][kk * 32 + 8 * g]);
#pragma unroll
      for (int mi = 0; mi < 4; ++mi)
#pragma unroll
        for (int ni = 0; ni < 4; ++ni)
          acc[mi][ni] = __builtin_amdgcn_mfma_f32_16x16x32_bf16(af[mi], bf[ni], acc[mi][ni], 0, 0, 0);
    }
    __syncthreads();
  }

  // epilogue: C frag layout col = l15, row = 4*g + reg (verified gfx950 mapping)
  if (mode == 0) {
    unsigned short* outb = (unsigned short*)outp;
#pragma unroll
    for (int mi = 0; mi < 4; ++mi) {
#pragma unroll
      for (int ni = 0; ni < 4; ++ni) {
        const int n = n0 + wn * 64 + ni * 16 + l15;
        const int h = n >> 6, hd = n & 63;
#pragma unroll
        for (int r = 0; r < 4; ++r) {
          const int m = m0 + wm * 64 + mi * 16 + 4 * g + r;
          const int b = m >> 11, s = m & 2047;
          outb[(((b * H_ + h) * S_) + s) * HD_ + hd] = f2bf(acc[mi][ni][r] * scale);
        }
      }
    }
  } else {
    float* outf = (float*)outp;
#pragma unroll
    for (int mi = 0; mi < 4; ++mi) {
#pragma unroll
      for (int ni = 0; ni < 4; ++ni) {
        const int n = n0 + wn * 64 + ni * 16 + l15;
        const float bv = bias[n];
#pragma unroll
        for (int r = 0; r < 4; ++r) {
          const int m = m0 + wm * 64 + mi * 16 + 4 * g + r;
          outf[m * 1024 + n] = acc[mi][ni][r] + bv;
        }
      }
    }
  }
}

// ---------------- causal flash attention ----------------
// Q/K/V: bf16 [B*H][S][HD], Q pre-scaled by HD^-0.5. Ctx out: bf16 [B][S][D].
// Block: 4 waves, 64 q-rows (16 per wave). KV tiles of 64.
__global__ __launch_bounds__(256) void attn_kernel(
    const unsigned short* __restrict__ Q,
    const unsigned short* __restrict__ K,
    const unsigned short* __restrict__ V,
    unsigned short* __restrict__ Ctx)
{
  __shared__ unsigned short Kl[64][72];      // K tile [s][hd]
  __shared__ unsigned short Vt[64][72];      // V tile transposed [hd][s]
  __shared__ unsigned short Pl[4][16][72];   // per-wave P tile [q][k]

  const int t    = threadIdx.x;
  const int lane = t & 63;
  const int w    = t >> 6;
  const int l15  = lane & 15;
  const int g    = lane >> 4;

  const int qt = blockIdx.x;       // q tile (64 rows)
  const int bh = blockIdx.y;       // b*H + h
  const long base = (long)bh * S_ * HD_;

  // Q fragments: lane holds row l15 of the wave's 16 q-rows, k = kk*32 + 8g + j
  const int qrow = qt * 64 + w * 16 + l15;
  s16x8 qf[2];
  qf[0] = *reinterpret_cast<const s16x8*>(&Q[base + (long)qrow * HD_ + 8 * g]);
  qf[1] = *reinterpret_cast<const s16x8*>(&Q[base + (long)qrow * HD_ + 32 + 8 * g]);

  f32x4 ctx[4];
#pragma unroll
  for (int ni = 0; ni < 4; ++ni) ctx[ni] = (f32x4){0.f, 0.f, 0.f, 0.f};
  float m_run[4], l_run[4];
#pragma unroll
  for (int r = 0; r < 4; ++r) { m_run[r] = -1e30f; l_run[r] = 0.f; }

  for (int kv = 0; kv <= qt; ++kv) {
    // ---- stage K tile row-major, V tile transposed ----
#pragma unroll
    for (int p = 0; p < 2; ++p) {
      const int r = p * 32 + (t >> 3);
      const int c = (t & 7) * 8;
      s16x8 kx = *reinterpret_cast<const s16x8*>(&K[base + (long)(kv * 64 + r) * HD_ + c]);
      *reinterpret_cast<s16x8*>(&Kl[r][c]) = kx;
      s16x8 vx = *reinterpret_cast<const s16x8*>(&V[base + (long)(kv * 64 + r) * HD_ + c]);
#pragma unroll
      for (int j = 0; j < 8; ++j) Vt[c + j][r] = (unsigned short)vx[j];
    }
    __syncthreads();

    // ---- S = Q K^T : D[q][kcol], lane holds cols l15+16f, rows 4g+reg ----
    f32x4 sacc[4];
#pragma unroll
    for (int f = 0; f < 4; ++f) sacc[f] = (f32x4){0.f, 0.f, 0.f, 0.f};
#pragma unroll
    for (int kk = 0; kk < 2; ++kk) {
#pragma unroll
      for (int f = 0; f < 4; ++f) {
        s16x8 kb = *reinterpret_cast<const s16x8*>(&Kl[l15 + 16 * f][kk * 32 + 8 * g]);
        sacc[f] = __builtin_amdgcn_mfma_f32_16x16x32_bf16(qf[kk], kb, sacc[f], 0, 0, 0);
      }
    }

    // causal mask (only the diagonal tile is partial)
    if (kv == qt) {
#pragma unroll
      for (int f = 0; f < 4; ++f) {
        const int kc = l15 + 16 * f;
#pragma unroll
        for (int r = 0; r < 4; ++r) {
          const int qr = w * 16 + 4 * g + r;
          if (kc > qr) sacc[f][r] = -1e30f;
        }
      }
    }

    // ---- online softmax: row stats live on the 16 lanes sharing g ----
    float mx[4];
#pragma unroll
    for (int r = 0; r < 4; ++r)
      mx[r] = fmaxf(fmaxf(sacc[0][r], sacc[1][r]), fmaxf(sacc[2][r], sacc[3][r]));
#pragma unroll
    for (int d = 1; d < 16; d <<= 1)
#pragma unroll
      for (int r = 0; r < 4; ++r) mx[r] = fmaxf(mx[r], __shfl_xor(mx[r], d));

    float alpha[4], psum[4];
#pragma unroll
    for (int r = 0; r < 4; ++r) {
      const float mn = fmaxf(m_run[r], mx[r]);
      alpha[r] = __expf(m_run[r] - mn);
      m_run[r] = mn;
      psum[r] = 0.f;
    }
#pragma unroll
    for (int f = 0; f < 4; ++f) {
#pragma unroll
      for (int r = 0; r < 4; ++r) {
        const float p = __expf(sacc[f][r] - m_run[r]);
        const unsigned short pb = f2bf(p);
        Pl[w][4 * g + r][l15 + 16 * f] = pb;
        psum[r] += bf2f(pb);   // sum what we actually feed the MFMA
      }
    }
#pragma unroll
    for (int d = 1; d < 16; d <<= 1)
#pragma unroll
      for (int r = 0; r < 4; ++r) psum[r] += __shfl_xor(psum[r], d);
#pragma unroll
    for (int r = 0; r < 4; ++r) l_run[r] = l_run[r] * alpha[r] + psum[r];
#pragma unroll
    for (int ni = 0; ni < 4; ++ni)
#pragma unroll
      for (int r = 0; r < 4; ++r) ctx[ni][r] *= alpha[r];

    // ---- ctx += P V : A = P (from per-wave LDS), B = V^T rows ----
#pragma unroll
    for (int kk = 0; kk < 2; ++kk) {
      s16x8 pa = *reinterpret_cast<const s16x8*>(&Pl[w][l15][kk * 32 + 8 * g]);
#pragma unroll
      for (int ni = 0; ni < 4; ++ni) {
        s16x8 vb = *reinterpret_cast<const s16x8*>(&Vt[l15 + 16 * ni][kk * 32 + 8 * g]);
        ctx[ni] = __builtin_amdgcn_mfma_f32_16x16x32_bf16(pa, vb, ctx[ni], 0, 0, 0);
      }
    }
    __syncthreads();   // protect Kl/Vt before next tile's staging
  }

  // ---- normalize + write ctx to [b][s][h*HD+d] bf16 ----
  const int b = bh >> 4, h = bh & 15;
#pragma unroll
  for (int ni = 0; ni < 4; ++ni) {
    const int d = h * 64 + l15 + 16 * ni;
#pragma unroll
    for (int r = 0; r < 4; ++r) {
      const int s = qt * 64 + w * 16 + 4 * g + r;
      Ctx[(long)(b * S_ + s) * D_ + d] = f2bf(ctx[ni][r] / l_run[r]);
    }
  }
}

// ---------------- launch ----------------
extern "C" void kernel_launch(void* const* d_in, const int* in_sizes, int n_in,
                              void* d_out, int out_size, void* d_ws, size_t ws_size,
                              hipStream_t stream) {
  const float* x  = (const float*)d_in[0];
  const float* Wq = (const float*)d_in[1];
  const float* Wk = (const float*)d_in[2];
  const float* Wv = (const float*)d_in[3];
  const float* Wo = (const float*)d_in[4];
  const float* bo = (const float*)d_in[5];
  float* out = (float*)d_out;

  char* ws = (char*)d_ws;
  const size_t MB = 1024 * 1024;
  // workspace map (48 MB total)
  unsigned short* xb  = (unsigned short*)(ws + 0 * MB);   // [4096][1024] bf16
  unsigned short* WqT = (unsigned short*)(ws + 8 * MB);   // [n][k] bf16
  unsigned short* WkT = (unsigned short*)(ws + 10 * MB);
  unsigned short* WvT = (unsigned short*)(ws + 12 * MB);
  unsigned short* Wob = (unsigned short*)(ws + 14 * MB);  // Wo[o][d] is already B^T layout
  unsigned short* Qb  = (unsigned short*)(ws + 16 * MB);  // [B*H][S][HD]
  unsigned short* Kb  = (unsigned short*)(ws + 24 * MB);
  unsigned short* Vb  = (unsigned short*)(ws + 32 * MB);
  unsigned short* Cx  = (unsigned short*)(ws + 40 * MB);  // [B][S][D] bf16

  cvt_kernel<<<(M_ * D_ / 4 + 255) / 256, 256, 0, stream>>>(x, xb, M_ * D_ / 4);
  cvt_kernel<<<(D_ * D_ / 4 + 255) / 256, 256, 0, stream>>>(Wo, Wob, D_ * D_ / 4);
  transpose_cvt<<<dim3(32, 32), dim3(32, 8), 0, stream>>>(Wq, WqT);
  transpose_cvt<<<dim3(32, 32), dim3(32, 8), 0, stream>>>(Wk, WkT);
  transpose_cvt<<<dim3(32, 32), dim3(32, 8), 0, stream>>>(Wv, WvT);

  dim3 gg(D_ / BN, M_ / BM);  // (8, 32)
  gemm_bt<<<gg, 256, 0, stream>>>(xb, WqT, (void*)Qb, nullptr, 0, 0.125f);  // Q pre-scaled
  gemm_bt<<<gg, 256, 0, stream>>>(xb, WkT, (void*)Kb, nullptr, 0, 1.0f);
  gemm_bt<<<gg, 256, 0, stream>>>(xb, WvT, (void*)Vb, nullptr, 0, 1.0f);

  attn_kernel<<<dim3(S_ / 64, B_ * H_), 256, 0, stream>>>(Qb, Kb, Vb, Cx);

  gemm_bt<<<gg, 256, 0, stream>>>(Cx, Wob, (void*)out, bo, 1, 1.0f);
}

// Round 2
// 198.094 us; speedup vs baseline: 1.3966x; 1.3966x over previous
//
#include <hip/hip_runtime.h>

// Problem constants (fixed by the reference)
#define B_  2
#define S_  2048
#define D_  1024
#define H_  16
#define HD_ 64
#define M_  (B_*S_)   // 4096 rows in all GEMMs

typedef __attribute__((ext_vector_type(8))) short s16x8;   // 8 bf16 (4 VGPRs) MFMA operand
typedef __attribute__((ext_vector_type(4))) float f32x4;   // MFMA accumulator

__device__ __forceinline__ unsigned short f2bf(float f) {
  unsigned int u = __builtin_bit_cast(unsigned int, f);
  u += 0x7fffu + ((u >> 16) & 1u);          // round-to-nearest-even
  return (unsigned short)(u >> 16);
}

// ---------------- elementwise f32 -> bf16 (x4 vectorized) ----------------
__global__ void cvt_kernel(const float* __restrict__ in, unsigned short* __restrict__ out, int n4) {
  int i = blockIdx.x * blockDim.x + threadIdx.x;
  if (i >= n4) return;
  float4 v = reinterpret_cast<const float4*>(in)[i];
  ushort4 o;
  o.x = f2bf(v.x); o.y = f2bf(v.y); o.z = f2bf(v.z); o.w = f2bf(v.w);
  reinterpret_cast<ushort4*>(out)[i] = o;
}

// ---------------- 1024x1024 transpose + convert: out[n][k] = in[k][n] ----------------
__global__ void transpose_cvt(const float* __restrict__ in, unsigned short* __restrict__ out) {
  __shared__ float tile[32][33];
  const int bx = blockIdx.x;   // input col tile (n)
  const int by = blockIdx.y;   // input row tile (k)
  const int tx = threadIdx.x;
  const int x = bx * 32 + tx;  // n
  for (int j = threadIdx.y; j < 32; j += 8) {
    tile[j][tx] = in[(by * 32 + j) * 1024 + x];   // in[k][n], coalesced
  }
  __syncthreads();
  const int xo = by * 32 + tx; // k (output col)
  for (int j = threadIdx.y; j < 32; j += 8) {
    out[(bx * 32 + j) * 1024 + xo] = f2bf(tile[tx][j]);  // out[n][k], coalesced
  }
}

// ---------------- bf16 MFMA GEMM, C[M,N] = A[M,K] * B[K,N] ----------------
// A: bf16 [4096][1024] row-major.  Bt: bf16 [N][K] (row n = column n of B).
// mode 0: write bf16 scattered to [b,h,s,hd] (Q/K projection), acc*scale.
// mode 1: write f32 [m][n] = acc + bias[n].
// mode 2: write bf16 V^T layout [b,h,hd,s] (packed ushort4 along s).
#define BM 128
#define BN 128
#define BK 64

__global__ __launch_bounds__(256) void gemm_bt(
    const unsigned short* __restrict__ A,
    const unsigned short* __restrict__ Bt,
    void* __restrict__ outp,
    const float* __restrict__ bias,
    const int mode, const float scale)
{
  __shared__ unsigned short As[BM][BK + 8];
  __shared__ unsigned short Bs[BN][BK + 8];

  const int t    = threadIdx.x;
  const int lane = t & 63;
  const int wid  = t >> 6;
  const int l15  = lane & 15;
  const int g    = lane >> 4;
  const int wm   = wid >> 1;   // 2x2 waves, each 64x64
  const int wn   = wid & 1;

  const int n0 = blockIdx.x * BN;
  const int m0 = blockIdx.y * BM;

  f32x4 acc[4][4];
#pragma unroll
  for (int i = 0; i < 4; ++i)
#pragma unroll
    for (int j = 0; j < 4; ++j)
      acc[i][j] = (f32x4){0.f, 0.f, 0.f, 0.f};

  for (int kt = 0; kt < 1024 / BK; ++kt) {
    const int k0 = kt * BK;
#pragma unroll
    for (int p = 0; p < 4; ++p) {
      const int lin = p * 256 + t;
      const int row = lin >> 3;
      const int col = (lin & 7) * 8;
      *reinterpret_cast<s16x8*>(&As[row][col]) =
          *reinterpret_cast<const s16x8*>(&A[(m0 + row) * 1024 + k0 + col]);
      *reinterpret_cast<s16x8*>(&Bs[row][col]) =
          *reinterpret_cast<const s16x8*>(&Bt[(n0 + row) * 1024 + k0 + col]);
    }
    __syncthreads();

#pragma unroll
    for (int kk = 0; kk < 2; ++kk) {
      s16x8 af[4], bf[4];
#pragma unroll
      for (int mi = 0; mi < 4; ++mi)
        af[mi] = *reinterpret_cast<const s16x8*>(&As[wm * 64 + mi * 16 + l15][kk * 32 + 8 * g]);
#pragma unroll
      for (int ni = 0; ni < 4; ++ni)
        bf[ni] = *reinterpret_cast<const s16x8*>(&Bs[wn * 64 + ni * 16 + l15][kk * 32 + 8 * g]);
#pragma unroll
      for (int mi = 0; mi < 4; ++mi)
#pragma unroll
        for (int ni = 0; ni < 4; ++ni)
          acc[mi][ni] = __builtin_amdgcn_mfma_f32_16x16x32_bf16(af[mi], bf[ni], acc[mi][ni], 0, 0, 0);
    }
    __syncthreads();
  }

  // C frag layout: col = l15, row = 4*g + reg
  if (mode == 0) {
    unsigned short* outb = (unsigned short*)outp;
#pragma unroll
    for (int mi = 0; mi < 4; ++mi) {
#pragma unroll
      for (int ni = 0; ni < 4; ++ni) {
        const int n = n0 + wn * 64 + ni * 16 + l15;
        const int h = n >> 6, hd = n & 63;
#pragma unroll
        for (int r = 0; r < 4; ++r) {
          const int m = m0 + wm * 64 + mi * 16 + 4 * g + r;
          const int b = m >> 11, s = m & 2047;
          outb[(((b * H_ + h) * S_) + s) * HD_ + hd] = f2bf(acc[mi][ni][r] * scale);
        }
      }
    }
  } else if (mode == 1) {
    float* outf = (float*)outp;
#pragma unroll
    for (int mi = 0; mi < 4; ++mi) {
#pragma unroll
      for (int ni = 0; ni < 4; ++ni) {
        const int n = n0 + wn * 64 + ni * 16 + l15;
        const float bv = bias[n];
#pragma unroll
        for (int r = 0; r < 4; ++r) {
          const int m = m0 + wm * 64 + mi * 16 + 4 * g + r;
          outf[m * 1024 + n] = acc[mi][ni][r] + bv;
        }
      }
    }
  } else {
    // V^T: out[((b*H+h)*HD + hd)*S + s], r-values are consecutive s -> ushort4
    unsigned short* outb = (unsigned short*)outp;
#pragma unroll
    for (int mi = 0; mi < 4; ++mi) {
#pragma unroll
      for (int ni = 0; ni < 4; ++ni) {
        const int n = n0 + wn * 64 + ni * 16 + l15;
        const int h = n >> 6, hd = n & 63;
        const int m = m0 + wm * 64 + mi * 16 + 4 * g;   // r = 0..3 consecutive
        const int b = m >> 11, s = m & 2047;
        ushort4 o;
        o.x = f2bf(acc[mi][ni][0]);
        o.y = f2bf(acc[mi][ni][1]);
        o.z = f2bf(acc[mi][ni][2]);
        o.w = f2bf(acc[mi][ni][3]);
        *reinterpret_cast<ushort4*>(&outb[(((b * H_ + h) * HD_) + hd) * S_ + s]) = o;
      }
    }
  }
}

// ---------------- causal flash attention (swapped-QK^T structure) ----------------
// Q/K: bf16 [B*H][S][HD] (Q pre-scaled by HD^-0.5 * log2(e)); VT: bf16 [B*H][HD][S].
// Ctx out: bf16 [B][S][D].
// Block = 2 waves; each wave owns 64 q-rows (4 subtiles of 16); KV tiles of 64.
// QK^T computed swapped: S^T[k][q] = mfma(A=K, B=Q)  -> lane owns q = lane&15.
// PV computed swapped:   ctx^T[hd][q] = mfma(A=V^T, B=P) -> q stays lane-local.
__global__ __launch_bounds__(128, 2) void attn_kernel(
    const unsigned short* __restrict__ Q,
    const unsigned short* __restrict__ K,
    const unsigned short* __restrict__ VT,
    unsigned short* __restrict__ Ctx)
{
  __shared__ unsigned short Kl[64][76];       // K tile [s][hd], pad->38 dwords/row
  __shared__ unsigned short Vt[64][76];       // V^T tile [hd][s]
  __shared__ unsigned short Pl[2][16][76];    // per-wave P [q][k] bf16

  const int t    = threadIdx.x;
  const int lane = t & 63;
  const int w    = t >> 6;        // 0..1
  const int l15  = lane & 15;
  const int g    = lane >> 4;

  const int bh = blockIdx.x;      // bh on x so same-bh blocks share an XCD L2
  const int qt = blockIdx.y;      // 128-row q tile
  const long base  = (long)bh * S_ * HD_;
  const long vbase = (long)bh * HD_ * S_;

  const int q0 = qt * 128 + w * 64;

  // Q fragments (B-operand layout: lane holds Q[q=l15][hd=kk*32+8g+j])
  s16x8 qf[4][2];
#pragma unroll
  for (int sq = 0; sq < 4; ++sq) {
    const long qr = q0 + sq * 16 + l15;
    qf[sq][0] = *reinterpret_cast<const s16x8*>(&Q[base + qr * HD_ + 8 * g]);
    qf[sq][1] = *reinterpret_cast<const s16x8*>(&Q[base + qr * HD_ + 32 + 8 * g]);
  }

  f32x4 ctx[4][4];   // [sq][ni] : ctx^T[hd=16ni+4g+r][q=l15]
#pragma unroll
  for (int sq = 0; sq < 4; ++sq)
#pragma unroll
    for (int ni = 0; ni < 4; ++ni) ctx[sq][ni] = (f32x4){0.f, 0.f, 0.f, 0.f};
  float m_run[4] = {-1e30f, -1e30f, -1e30f, -1e30f};
  float l_run[4] = {0.f, 0.f, 0.f, 0.f};

  const int ntiles = 2 * qt + 2;
  for (int kv = 0; kv < ntiles; ++kv) {
    // ---- stage K tile and V^T tile (vector loads, coalesced) ----
    {
      const int c0 = (t & 7) * 8;
      const int r0 = t >> 3;           // 0..15
#pragma unroll
      for (int p = 0; p < 4; ++p) {
        const int row = r0 + p * 16;
        *reinterpret_cast<s16x8*>(&Kl[row][c0]) =
            *reinterpret_cast<const s16x8*>(&K[base + (long)(kv * 64 + row) * HD_ + c0]);
        *reinterpret_cast<s16x8*>(&Vt[row][c0]) =
            *reinterpret_cast<const s16x8*>(&VT[vbase + (long)row * S_ + kv * 64 + c0]);
      }
    }
    __syncthreads();

    // wave 0's last tile can be entirely above the diagonal -> skip compute
    const bool active = (kv * 64) <= (q0 + 63);
    if (active) {
      // hoist K (A-operand rows k) and V^T (A-operand rows hd) fragments
      s16x8 kb[2][4], vb[2][4];
#pragma unroll
      for (int kk = 0; kk < 2; ++kk)
#pragma unroll
        for (int f = 0; f < 4; ++f) {
          kb[kk][f] = *reinterpret_cast<const s16x8*>(&Kl[16 * f + l15][kk * 32 + 8 * g]);
          vb[kk][f] = *reinterpret_cast<const s16x8*>(&Vt[16 * f + l15][kk * 32 + 8 * g]);
        }

#pragma unroll
      for (int sq = 0; sq < 4; ++sq) {
        // S^T tile: sacc[f] rows k = 16f+4g+r, col q = l15  (log2-units)
        f32x4 sacc[4];
#pragma unroll
        for (int f = 0; f < 4; ++f) sacc[f] = (f32x4){0.f, 0.f, 0.f, 0.f};
#pragma unroll
        for (int kk = 0; kk < 2; ++kk)
#pragma unroll
          for (int f = 0; f < 4; ++f)
            sacc[f] = __builtin_amdgcn_mfma_f32_16x16x32_bf16(kb[kk][f], qf[sq][kk], sacc[f], 0, 0, 0);

        const int qrow = q0 + sq * 16 + l15;
        if (kv >= 2 * qt) {   // possibly-partial (diagonal) tiles
#pragma unroll
          for (int f = 0; f < 4; ++f)
#pragma unroll
            for (int r = 0; r < 4; ++r)
              if (kv * 64 + 16 * f + 4 * g + r > qrow) sacc[f][r] = -1e30f;
        }

        // row max: 15 in-lane + 2 shfl (4 lanes share q=l15)
        float mx = sacc[0][0];
#pragma unroll
        for (int f = 0; f < 4; ++f)
#pragma unroll
          for (int r = 0; r < 4; ++r) mx = fmaxf(mx, sacc[f][r]);
        mx = fmaxf(mx, __shfl_xor(mx, 16));
        mx = fmaxf(mx, __shfl_xor(mx, 32));
        const float mn = fmaxf(m_run[sq], mx);
        const float alpha = __builtin_amdgcn_exp2f(m_run[sq] - mn);
        m_run[sq] = mn;

        float ps = 0.f;
        unsigned int pk0[4], pk1[4];
#pragma unroll
        for (int f = 0; f < 4; ++f) {
          const float p0 = __builtin_amdgcn_exp2f(sacc[f][0] - mn);
          const float p1 = __builtin_amdgcn_exp2f(sacc[f][1] - mn);
          const float p2 = __builtin_amdgcn_exp2f(sacc[f][2] - mn);
          const float p3 = __builtin_amdgcn_exp2f(sacc[f][3] - mn);
          ps += (p0 + p1) + (p2 + p3);
          asm("v_cvt_pk_bf16_f32 %0, %1, %2" : "=v"(pk0[f]) : "v"(p0), "v"(p1));
          asm("v_cvt_pk_bf16_f32 %0, %1, %2" : "=v"(pk1[f]) : "v"(p2), "v"(p3));
        }
        ps += __shfl_xor(ps, 16);
        ps += __shfl_xor(ps, 32);
        l_run[sq] = l_run[sq] * alpha + ps;
#pragma unroll
        for (int ni = 0; ni < 4; ++ni)
#pragma unroll
          for (int r = 0; r < 4; ++r) ctx[sq][ni][r] *= alpha;

        // P -> LDS: one 8B vector write per f (k = 16f+4g..+3 for q=l15)
#pragma unroll
        for (int f = 0; f < 4; ++f) {
          uint2 pr; pr.x = pk0[f]; pr.y = pk1[f];
          *reinterpret_cast<uint2*>(&Pl[w][l15][16 * f + 4 * g]) = pr;
        }
        // PV: B-frag P[q=l15][k=kk*32+8g+j], A-frag V^T rows hd
#pragma unroll
        for (int kk = 0; kk < 2; ++kk) {
          const s16x8 pf = *reinterpret_cast<const s16x8*>(&Pl[w][l15][kk * 32 + 8 * g]);
#pragma unroll
          for (int ni = 0; ni < 4; ++ni)
            ctx[sq][ni] = __builtin_amdgcn_mfma_f32_16x16x32_bf16(vb[kk][ni], pf, ctx[sq][ni], 0, 0, 0);
        }
      }
    }
    __syncthreads();
  }

  // ---- normalize + write ctx^T to [b][s][h*64+hd], packed 4 bf16 along hd ----
  const int b = bh >> 4, h = bh & 15;
#pragma unroll
  for (int sq = 0; sq < 4; ++sq) {
    const float inv = 1.f / l_run[sq];
    const long srow = q0 + sq * 16 + l15;
#pragma unroll
    for (int ni = 0; ni < 4; ++ni) {
      ushort4 o;
      o.x = f2bf(ctx[sq][ni][0] * inv);
      o.y = f2bf(ctx[sq][ni][1] * inv);
      o.z = f2bf(ctx[sq][ni][2] * inv);
      o.w = f2bf(ctx[sq][ni][3] * inv);
      *reinterpret_cast<ushort4*>(&Ctx[((long)b * S_ + srow) * D_ + h * 64 + 16 * ni + 4 * g]) = o;
    }
  }
}

// ---------------- launch ----------------
extern "C" void kernel_launch(void* const* d_in, const int* in_sizes, int n_in,
                              void* d_out, int out_size, void* d_ws, size_t ws_size,
                              hipStream_t stream) {
  const float* x  = (const float*)d_in[0];
  const float* Wq = (const float*)d_in[1];
  const float* Wk = (const float*)d_in[2];
  const float* Wv = (const float*)d_in[3];
  const float* Wo = (const float*)d_in[4];
  const float* bo = (const float*)d_in[5];
  float* out = (float*)d_out;

  char* ws = (char*)d_ws;
  const size_t MB = 1024 * 1024;
  unsigned short* xb  = (unsigned short*)(ws + 0 * MB);   // [4096][1024] bf16
  unsigned short* WqT = (unsigned short*)(ws + 8 * MB);   // [n][k] bf16
  unsigned short* WkT = (unsigned short*)(ws + 10 * MB);
  unsigned short* WvT = (unsigned short*)(ws + 12 * MB);
  unsigned short* Wob = (unsigned short*)(ws + 14 * MB);  // Wo[o][d] already B^T layout
  unsigned short* Qb  = (unsigned short*)(ws + 16 * MB);  // [B*H][S][HD]
  unsigned short* Kb  = (unsigned short*)(ws + 24 * MB);  // [B*H][S][HD]
  unsigned short* VTb = (unsigned short*)(ws + 32 * MB);  // [B*H][HD][S]
  unsigned short* Cx  = (unsigned short*)(ws + 40 * MB);  // [B][S][D] bf16

  cvt_kernel<<<(M_ * D_ / 4 + 255) / 256, 256, 0, stream>>>(x, xb, M_ * D_ / 4);
  cvt_kernel<<<(D_ * D_ / 4 + 255) / 256, 256, 0, stream>>>(Wo, Wob, D_ * D_ / 4);
  transpose_cvt<<<dim3(32, 32), dim3(32, 8), 0, stream>>>(Wq, WqT);
  transpose_cvt<<<dim3(32, 32), dim3(32, 8), 0, stream>>>(Wk, WkT);
  transpose_cvt<<<dim3(32, 32), dim3(32, 8), 0, stream>>>(Wv, WvT);

  dim3 gg(D_ / BN, M_ / BM);  // (8, 32)
  // Q pre-scaled by HD^-0.5 * log2(e) so softmax runs in exp2 domain
  gemm_bt<<<gg, 256, 0, stream>>>(xb, WqT, (void*)Qb, nullptr, 0, 0.18033688011112042f);
  gemm_bt<<<gg, 256, 0, stream>>>(xb, WkT, (void*)Kb, nullptr, 0, 1.0f);
  gemm_bt<<<gg, 256, 0, stream>>>(xb, WvT, (void*)VTb, nullptr, 2, 1.0f);

  attn_kernel<<<dim3(B_ * H_, S_ / 128), 128, 0, stream>>>(Qb, Kb, VTb, Cx);

  gemm_bt<<<gg, 256, 0, stream>>>(Cx, Wob, (void*)out, bo, 1, 1.0f);
}

// Round 3
// 178.948 us; speedup vs baseline: 1.5461x; 1.1070x over previous
//
#include <hip/hip_runtime.h>

// Problem constants (fixed by the reference)
#define B_  2
#define S_  2048
#define D_  1024
#define H_  16
#define HD_ 64
#define M_  (B_*S_)   // 4096 rows in all GEMMs

typedef __attribute__((ext_vector_type(8))) short s16x8;   // 8 bf16 (4 VGPRs) MFMA operand
typedef __attribute__((ext_vector_type(4))) float f32x4;   // MFMA accumulator

__device__ __forceinline__ unsigned short f2bf(float f) {
  unsigned int u = __builtin_bit_cast(unsigned int, f);
  u += 0x7fffu + ((u >> 16) & 1u);          // round-to-nearest-even
  return (unsigned short)(u >> 16);
}

// async global->LDS, 16B per lane; LDS dest must be wave-uniform base (HW adds lane*16)
__device__ __forceinline__ void gload_lds16(const unsigned short* g, unsigned short* l) {
  __builtin_amdgcn_global_load_lds((const __attribute__((address_space(1))) void*)g,
                                   (__attribute__((address_space(3))) void*)l, 16, 0, 0);
}

// ---------------- elementwise f32 -> bf16 (x4 vectorized) ----------------
__global__ void cvt_kernel(const float* __restrict__ in, unsigned short* __restrict__ out, int n4) {
  int i = blockIdx.x * blockDim.x + threadIdx.x;
  if (i >= n4) return;
  float4 v = reinterpret_cast<const float4*>(in)[i];
  ushort4 o;
  o.x = f2bf(v.x); o.y = f2bf(v.y); o.z = f2bf(v.z); o.w = f2bf(v.w);
  reinterpret_cast<ushort4*>(out)[i] = o;
}

// ---------------- 3x 1024x1024 transpose+convert in one dispatch ----------------
__global__ void transpose_cvt3(const float* __restrict__ W0, const float* __restrict__ W1,
                               const float* __restrict__ W2, unsigned short* __restrict__ dstBase) {
  __shared__ float tile[32][33];
  const float* in = blockIdx.z == 0 ? W0 : (blockIdx.z == 1 ? W1 : W2);
  unsigned short* out = dstBase + (size_t)blockIdx.z * 1024 * 1024;
  const int bx = blockIdx.x, by = blockIdx.y, tx = threadIdx.x;
  const int x = bx * 32 + tx;
  for (int j = threadIdx.y; j < 32; j += 8)
    tile[j][tx] = in[(by * 32 + j) * 1024 + x];
  __syncthreads();
  const int xo = by * 32 + tx;
  for (int j = threadIdx.y; j < 32; j += 8)
    out[(bx * 32 + j) * 1024 + xo] = f2bf(tile[tx][j]);
}

// ---------------- bf16 MFMA GEMM (m97-style global_load_lds staging) ----------------
// A: bf16 [M][1024] row-major. Bt: bf16 [N][1024] (row n = column n of B).
// mode 0 (fused QKV, N=3072): n<1024 -> Q scatter [b,h,s,hd] * qscale (exp2-domain),
//                             1024..2047 -> K scatter, 2048..3071 -> V^T [b,h,hd,s].
// mode 1: C f32 [m][1024] = acc + bias[n].
#define BM 128
#define BN 128
#define BK 64

__global__ __launch_bounds__(256) void gemm_bt(
    const unsigned short* __restrict__ A,
    const unsigned short* __restrict__ Bt,
    void* __restrict__ out0, void* __restrict__ out1, void* __restrict__ out2,
    const float* __restrict__ bias,
    const int mode, const float qscale)
{
  __shared__ unsigned short As[BM * BK];   // linear: global_load_lds needs contiguous dest
  __shared__ unsigned short Bs[BN * BK];

  const int t    = threadIdx.x;
  const int lane = t & 63;
  const int wid  = t >> 6;
  const int l15  = lane & 15;
  const int g    = lane >> 4;
  const int wm   = wid >> 1;   // 2x2 waves, each 64x64
  const int wn   = wid & 1;

  const int n0 = blockIdx.x * BN;
  const int m0 = blockIdx.y * BM;

  // staging map: chunk c (0..15) = 8 rows = 1KB; lane l -> row c*8+l/8, col (l&7)*8
  const int lrow = lane >> 3;
  const int lcol = (lane & 7) * 8;

  f32x4 acc[4][4];
#pragma unroll
  for (int i = 0; i < 4; ++i)
#pragma unroll
    for (int j = 0; j < 4; ++j)
      acc[i][j] = (f32x4){0.f, 0.f, 0.f, 0.f};

  for (int kt = 0; kt < 1024 / BK; ++kt) {
    const int k0 = kt * BK;
#pragma unroll
    for (int p = 0; p < 4; ++p) {
      const int c = p * 4 + wid;            // wave-uniform chunk id
      const int row = c * 8 + lrow;
      gload_lds16(&A[(size_t)(m0 + row) * 1024 + k0 + lcol], &As[c * 512]);
      gload_lds16(&Bt[(size_t)(n0 + row) * 1024 + k0 + lcol], &Bs[c * 512]);
    }
    __syncthreads();   // drains vmcnt before LDS reads

#pragma unroll
    for (int kk = 0; kk < 2; ++kk) {
      s16x8 af[4], bf[4];
#pragma unroll
      for (int mi = 0; mi < 4; ++mi)
        af[mi] = *reinterpret_cast<const s16x8*>(&As[(wm * 64 + mi * 16 + l15) * BK + kk * 32 + 8 * g]);
#pragma unroll
      for (int ni = 0; ni < 4; ++ni)
        bf[ni] = *reinterpret_cast<const s16x8*>(&Bs[(wn * 64 + ni * 16 + l15) * BK + kk * 32 + 8 * g]);
#pragma unroll
      for (int mi = 0; mi < 4; ++mi)
#pragma unroll
        for (int ni = 0; ni < 4; ++ni)
          acc[mi][ni] = __builtin_amdgcn_mfma_f32_16x16x32_bf16(af[mi], bf[ni], acc[mi][ni], 0, 0, 0);
    }
    __syncthreads();
  }

  // C frag layout: col = l15, row = 4*g + reg
  if (mode == 0) {
    const int sel = n0 >> 10;          // whole block lives in one of Q/K/V
    const int nl0 = n0 & 1023;
    if (sel < 2) {
      unsigned short* outb = (unsigned short*)(sel == 0 ? out0 : out1);
      const float sc = (sel == 0) ? qscale : 1.0f;
#pragma unroll
      for (int mi = 0; mi < 4; ++mi) {
#pragma unroll
        for (int ni = 0; ni < 4; ++ni) {
          const int n = nl0 + wn * 64 + ni * 16 + l15;
          const int h = n >> 6, hd = n & 63;
#pragma unroll
          for (int r = 0; r < 4; ++r) {
            const int m = m0 + wm * 64 + mi * 16 + 4 * g + r;
            const int b = m >> 11, s = m & 2047;
            outb[(((b * H_ + h) * S_) + s) * HD_ + hd] = f2bf(acc[mi][ni][r] * sc);
          }
        }
      }
    } else {
      // V^T: out[((b*H+h)*HD + hd)*S + s], r-values consecutive in s -> ushort4
      unsigned short* outb = (unsigned short*)out2;
#pragma unroll
      for (int mi = 0; mi < 4; ++mi) {
#pragma unroll
        for (int ni = 0; ni < 4; ++ni) {
          const int n = nl0 + wn * 64 + ni * 16 + l15;
          const int h = n >> 6, hd = n & 63;
          const int m = m0 + wm * 64 + mi * 16 + 4 * g;
          const int b = m >> 11, s = m & 2047;
          ushort4 o;
          o.x = f2bf(acc[mi][ni][0]);
          o.y = f2bf(acc[mi][ni][1]);
          o.z = f2bf(acc[mi][ni][2]);
          o.w = f2bf(acc[mi][ni][3]);
          *reinterpret_cast<ushort4*>(&outb[(((b * H_ + h) * HD_) + hd) * S_ + s]) = o;
        }
      }
    }
  } else {
    float* outf = (float*)out0;
#pragma unroll
    for (int mi = 0; mi < 4; ++mi) {
#pragma unroll
      for (int ni = 0; ni < 4; ++ni) {
        const int n = n0 + wn * 64 + ni * 16 + l15;
        const float bv = bias[n];
#pragma unroll
        for (int r = 0; r < 4; ++r) {
          const int m = m0 + wm * 64 + mi * 16 + 4 * g + r;
          outf[m * 1024 + n] = acc[mi][ni][r] + bv;
        }
      }
    }
  }
}

// ---------------- causal flash attention: in-block kv-split, barrier-free main loop ----
// Q/K: bf16 [B*H][S][HD] (Q pre-scaled by HD^-0.5*log2e); VT: bf16 [B*H][HD][S].
// Grid (32 bh, 32 qt'), qt = 31-qt' (big blocks first). Block = 4 waves, ALL on the
// same 64 q-rows; wave w takes kv tiles w, w+4, ... (<= qt). K/V^T fragments load
// straight from global (L2-resident) -> no K/V LDS, no in-loop barriers.
// End: 3-step online-softmax merge via one f32 LDS buffer.
__global__ __launch_bounds__(256) void attn_kernel(
    const unsigned short* __restrict__ Q,
    const unsigned short* __restrict__ K,
    const unsigned short* __restrict__ VT,
    unsigned short* __restrict__ Ctx)
{
  __shared__ unsigned short Pl[4][16][76];   // per-wave P [q][k] bf16
  __shared__ float ctxbuf[64][68];           // merge buffer [q][hd]
  __shared__ float mbuf[64], lbuf[64];

  const int t    = threadIdx.x;
  const int lane = t & 63;
  const int w    = t >> 6;        // 0..3
  const int l15  = lane & 15;
  const int g    = lane >> 4;

  const int bh = blockIdx.x;
  const int qt = 31 - blockIdx.y;            // descending work size
  const long base  = (long)bh * S_ * HD_;
  const long vbase = (long)bh * HD_ * S_;
  const int q0 = qt * 64;

  // Q fragments (B-operand: lane holds Q[q=l15][hd=kk*32+8g+j])
  s16x8 qf[4][2];
#pragma unroll
  for (int sq = 0; sq < 4; ++sq) {
    const long qr = q0 + sq * 16 + l15;
    qf[sq][0] = *reinterpret_cast<const s16x8*>(&Q[base + qr * HD_ + 8 * g]);
    qf[sq][1] = *reinterpret_cast<const s16x8*>(&Q[base + qr * HD_ + 32 + 8 * g]);
  }

  f32x4 ctx[4][4];   // [sq][ni] : ctx^T[hd=16ni+4g+r][q=l15], unnormalized
#pragma unroll
  for (int sq = 0; sq < 4; ++sq)
#pragma unroll
    for (int ni = 0; ni < 4; ++ni) ctx[sq][ni] = (f32x4){0.f, 0.f, 0.f, 0.f};
  float m_run[4] = {-1e30f, -1e30f, -1e30f, -1e30f};
  float l_run[4] = {0.f, 0.f, 0.f, 0.f};

  for (int kv = w; kv <= qt; kv += 4) {
    const unsigned short* Kt = &K[base + (long)kv * 64 * HD_];
    const unsigned short* Vp = &VT[vbase + kv * 64];
    // K rows (A-operand, rows k) and V^T rows (A-operand, rows hd) from global
    s16x8 kb[2][4], vb[2][4];
#pragma unroll
    for (int kk = 0; kk < 2; ++kk)
#pragma unroll
      for (int f = 0; f < 4; ++f) {
        kb[kk][f] = *reinterpret_cast<const s16x8*>(&Kt[(16 * f + l15) * HD_ + kk * 32 + 8 * g]);
        vb[kk][f] = *reinterpret_cast<const s16x8*>(&Vp[(long)(16 * f + l15) * S_ + kk * 32 + 8 * g]);
      }

#pragma unroll
    for (int sq = 0; sq < 4; ++sq) {
      f32x4 sacc[4];
#pragma unroll
      for (int f = 0; f < 4; ++f) sacc[f] = (f32x4){0.f, 0.f, 0.f, 0.f};
#pragma unroll
      for (int kk = 0; kk < 2; ++kk)
#pragma unroll
        for (int f = 0; f < 4; ++f)
          sacc[f] = __builtin_amdgcn_mfma_f32_16x16x32_bf16(kb[kk][f], qf[sq][kk], sacc[f], 0, 0, 0);

      const int qrow = q0 + sq * 16 + l15;
      if (kv == qt) {   // only the diagonal tile is partial
#pragma unroll
        for (int f = 0; f < 4; ++f)
#pragma unroll
          for (int r = 0; r < 4; ++r)
            if (kv * 64 + 16 * f + 4 * g + r > qrow) sacc[f][r] = -1e30f;
      }

      // row max: 15 in-lane + 2 shfl (4 lanes share q=l15)
      float mx = sacc[0][0];
#pragma unroll
      for (int f = 0; f < 4; ++f)
#pragma unroll
        for (int r = 0; r < 4; ++r) mx = fmaxf(mx, sacc[f][r]);
      mx = fmaxf(mx, __shfl_xor(mx, 16));
      mx = fmaxf(mx, __shfl_xor(mx, 32));
      const float mn = fmaxf(m_run[sq], mx);
      const float alpha = __builtin_amdgcn_exp2f(m_run[sq] - mn);
      m_run[sq] = mn;

      float ps = 0.f;
      unsigned int pk0[4], pk1[4];
#pragma unroll
      for (int f = 0; f < 4; ++f) {
        const float p0 = __builtin_amdgcn_exp2f(sacc[f][0] - mn);
        const float p1 = __builtin_amdgcn_exp2f(sacc[f][1] - mn);
        const float p2 = __builtin_amdgcn_exp2f(sacc[f][2] - mn);
        const float p3 = __builtin_amdgcn_exp2f(sacc[f][3] - mn);
        ps += (p0 + p1) + (p2 + p3);
        asm("v_cvt_pk_bf16_f32 %0, %1, %2" : "=v"(pk0[f]) : "v"(p0), "v"(p1));
        asm("v_cvt_pk_bf16_f32 %0, %1, %2" : "=v"(pk1[f]) : "v"(p2), "v"(p3));
      }
      ps += __shfl_xor(ps, 16);
      ps += __shfl_xor(ps, 32);
      l_run[sq] = l_run[sq] * alpha + ps;
#pragma unroll
      for (int ni = 0; ni < 4; ++ni)
#pragma unroll
        for (int r = 0; r < 4; ++r) ctx[sq][ni][r] *= alpha;

      // P -> per-wave LDS (8B vector writes), read back as PV B-fragments
#pragma unroll
      for (int f = 0; f < 4; ++f) {
        uint2 pr; pr.x = pk0[f]; pr.y = pk1[f];
        *reinterpret_cast<uint2*>(&Pl[w][l15][16 * f + 4 * g]) = pr;
      }
#pragma unroll
      for (int kk = 0; kk < 2; ++kk) {
        const s16x8 pf = *reinterpret_cast<const s16x8*>(&Pl[w][l15][kk * 32 + 8 * g]);
#pragma unroll
        for (int ni = 0; ni < 4; ++ni)
          ctx[sq][ni] = __builtin_amdgcn_mfma_f32_16x16x32_bf16(vb[kk][ni], pf, ctx[sq][ni], 0, 0, 0);
      }
    }
  }

  // ---- merge 4 waves' (m, l, ctx) -> wave 0 ----
  __syncthreads();
  for (int src = 3; src >= 1; --src) {
    if (w == src) {
#pragma unroll
      for (int sq = 0; sq < 4; ++sq) {
#pragma unroll
        for (int ni = 0; ni < 4; ++ni)
          *reinterpret_cast<f32x4*>(&ctxbuf[sq * 16 + l15][16 * ni + 4 * g]) = ctx[sq][ni];
        if (g == 0) { mbuf[sq * 16 + l15] = m_run[sq]; lbuf[sq * 16 + l15] = l_run[sq]; }
      }
    }
    __syncthreads();
    if (w == 0) {
#pragma unroll
      for (int sq = 0; sq < 4; ++sq) {
        const int qi = sq * 16 + l15;
        const float ms = mbuf[qi], ls = lbuf[qi];
        const float M  = fmaxf(m_run[sq], ms);
        const float a0 = __builtin_amdgcn_exp2f(m_run[sq] - M);
        const float a1 = __builtin_amdgcn_exp2f(ms - M);
        m_run[sq] = M;
        l_run[sq] = l_run[sq] * a0 + ls * a1;
#pragma unroll
        for (int ni = 0; ni < 4; ++ni) {
          const f32x4 cs = *reinterpret_cast<const f32x4*>(&ctxbuf[qi][16 * ni + 4 * g]);
#pragma unroll
          for (int r = 0; r < 4; ++r)
            ctx[sq][ni][r] = ctx[sq][ni][r] * a0 + cs[r] * a1;
        }
      }
    }
    __syncthreads();
  }

  if (w == 0) {
    const int b = bh >> 4, h = bh & 15;
#pragma unroll
    for (int sq = 0; sq < 4; ++sq) {
      const float inv = 1.f / l_run[sq];
      const long srow = q0 + sq * 16 + l15;
#pragma unroll
      for (int ni = 0; ni < 4; ++ni) {
        ushort4 o;
        o.x = f2bf(ctx[sq][ni][0] * inv);
        o.y = f2bf(ctx[sq][ni][1] * inv);
        o.z = f2bf(ctx[sq][ni][2] * inv);
        o.w = f2bf(ctx[sq][ni][3] * inv);
        *reinterpret_cast<ushort4*>(&Ctx[((long)b * S_ + srow) * D_ + h * 64 + 16 * ni + 4 * g]) = o;
      }
    }
  }
}

// ---------------- launch ----------------
extern "C" void kernel_launch(void* const* d_in, const int* in_sizes, int n_in,
                              void* d_out, int out_size, void* d_ws, size_t ws_size,
                              hipStream_t stream) {
  const float* x  = (const float*)d_in[0];
  const float* Wq = (const float*)d_in[1];
  const float* Wk = (const float*)d_in[2];
  const float* Wv = (const float*)d_in[3];
  const float* Wo = (const float*)d_in[4];
  const float* bo = (const float*)d_in[5];
  float* out = (float*)d_out;

  char* ws = (char*)d_ws;
  const size_t MB = 1024 * 1024;
  unsigned short* xb  = (unsigned short*)(ws + 0 * MB);   // [4096][1024] bf16
  unsigned short* WT  = (unsigned short*)(ws + 8 * MB);   // [3072][1024] bf16: Wq^T|Wk^T|Wv^T
  unsigned short* Wob = (unsigned short*)(ws + 14 * MB);  // Wo[o][d] already B^T layout
  unsigned short* Qb  = (unsigned short*)(ws + 16 * MB);  // [B*H][S][HD]
  unsigned short* Kb  = (unsigned short*)(ws + 24 * MB);  // [B*H][S][HD]
  unsigned short* VTb = (unsigned short*)(ws + 32 * MB);  // [B*H][HD][S]
  unsigned short* Cx  = (unsigned short*)(ws + 40 * MB);  // [B][S][D] bf16

  cvt_kernel<<<(M_ * D_ / 4 + 255) / 256, 256, 0, stream>>>(x, xb, M_ * D_ / 4);
  cvt_kernel<<<(D_ * D_ / 4 + 255) / 256, 256, 0, stream>>>(Wo, Wob, D_ * D_ / 4);
  transpose_cvt3<<<dim3(32, 32, 3), dim3(32, 8), 0, stream>>>(Wq, Wk, Wv, WT);

  // fused QKV projection: N = 3072, Q pre-scaled by HD^-0.5 * log2(e)
  gemm_bt<<<dim3(3 * D_ / BN, M_ / BM), 256, 0, stream>>>(
      xb, WT, (void*)Qb, (void*)Kb, (void*)VTb, nullptr, 0, 0.18033688011112042f);

  attn_kernel<<<dim3(B_ * H_, S_ / 64), 256, 0, stream>>>(Qb, Kb, VTb, Cx);

  gemm_bt<<<dim3(D_ / BN, M_ / BM), 256, 0, stream>>>(
      Cx, Wob, (void*)out, nullptr, nullptr, bo, 1, 1.0f);
}